// Round 1
// baseline (130.679 us; speedup 1.0000x reference)
//
#include <hip/hip_runtime.h>
#include <math.h>

#ifndef M_PI
#define M_PI 3.14159265358979323846
#endif

#define B_ 8
#define S_ 197
#define E_ 384
#define H_ 6
#define D_ 64
#define N_ (B_*S_)          // 1576
#define EN ((size_t)E_*N_)  // 605184
#define ATT_LD 200
#define NBLK_ADD 150        // 6*25 blocks per projection

// ---------------------------------------------------------------------------
// Kernel 1: adder 1x1 for q,k,v.  Y[p][co][n] = -sum_ci |x2d[ci][n]-w[co][ci]|
// grid (6, 25, 3) block 256.  Also emits per-block (sum, sumsq) partials.
// ---------------------------------------------------------------------------
__global__ __launch_bounds__(256) void k_adder(
    const float* __restrict__ x,
    const float* __restrict__ wq, const float* __restrict__ wk,
    const float* __restrict__ wv,
    float* __restrict__ Y, float* __restrict__ partials)
{
  const int p = blockIdx.z;
  const float* __restrict__ w = (p == 0) ? wq : (p == 1) ? wk : wv;
  const int co0 = blockIdx.x * 64;
  const int n0  = blockIdx.y * 64;

  __shared__ float Xs[16][64];   // [ci_local][n_local]
  __shared__ float Ws[16][64];   // [ci_local][co_local] (transposed)
  __shared__ float red[8];

  const int tid = threadIdx.x;
  const int tx = tid & 15;       // n direction
  const int ty = tid >> 4;       // co direction

  float acc[4][4];
  #pragma unroll
  for (int i = 0; i < 4; ++i)
    #pragma unroll
    for (int j = 0; j < 4; ++j) acc[i][j] = 0.f;

  for (int ci0 = 0; ci0 < E_; ci0 += 16) {
    // stage X tile: 16 rows (ci) x 64 cols (n)
    {
      int r = tid >> 4, c = (tid & 15) * 4;
      int n = n0 + c;
      float4 v = make_float4(0.f, 0.f, 0.f, 0.f);
      if (n + 3 < N_) v = *(const float4*)(x + (size_t)(ci0 + r) * N_ + n);
      *(float4*)(&Xs[r][c]) = v;
    }
    // stage W tile transposed: rows co, cols ci -> Ws[ci][co]
    {
      int r = tid >> 2, c = (tid & 3) * 4;
      float4 v = *(const float4*)(w + (size_t)(co0 + r) * E_ + ci0 + c);
      Ws[c + 0][r] = v.x; Ws[c + 1][r] = v.y;
      Ws[c + 2][r] = v.z; Ws[c + 3][r] = v.w;
    }
    __syncthreads();
    #pragma unroll
    for (int cc = 0; cc < 16; ++cc) {
      float4 xv = *(const float4*)(&Xs[cc][tx * 4]);
      float4 wv4 = *(const float4*)(&Ws[cc][ty * 4]);
      float xa[4] = {xv.x, xv.y, xv.z, xv.w};
      float wa[4] = {wv4.x, wv4.y, wv4.z, wv4.w};
      #pragma unroll
      for (int i = 0; i < 4; ++i)
        #pragma unroll
        for (int j = 0; j < 4; ++j)
          acc[i][j] += fabsf(xa[j] - wa[i]);
    }
    __syncthreads();
  }

  float s1 = 0.f, s2 = 0.f;
  const int nb = n0 + tx * 4;
  if (nb + 3 < N_) {   // N_ % 4 == 0 -> float4 fully valid or fully invalid
    #pragma unroll
    for (int i = 0; i < 4; ++i) {
      int co = co0 + ty * 4 + i;
      float4 yv;
      yv.x = -acc[i][0]; yv.y = -acc[i][1];
      yv.z = -acc[i][2]; yv.w = -acc[i][3];
      *(float4*)(Y + (size_t)p * EN + (size_t)co * N_ + nb) = yv;
      s1 += yv.x + yv.y + yv.z + yv.w;
      s2 += yv.x * yv.x + yv.y * yv.y + yv.z * yv.z + yv.w * yv.w;
    }
  }
  // block reduction of (s1, s2)
  #pragma unroll
  for (int off = 32; off > 0; off >>= 1) {
    s1 += __shfl_down(s1, off);
    s2 += __shfl_down(s2, off);
  }
  int wid = tid >> 6, lane = tid & 63;
  if (lane == 0) { red[wid * 2] = s1; red[wid * 2 + 1] = s2; }
  __syncthreads();
  if (tid == 0) {
    float t1 = red[0] + red[2] + red[4] + red[6];
    float t2 = red[1] + red[3] + red[5] + red[7];
    int blk = blockIdx.x * gridDim.y + blockIdx.y;
    partials[((size_t)p * NBLK_ADD + blk) * 2 + 0] = t1;
    partials[((size_t)p * NBLK_ADD + blk) * 2 + 1] = t2;
  }
}

// ---------------------------------------------------------------------------
// Kernel 2: reduce partials -> (mean, rstd) per projection.  grid(3) block 256
// ---------------------------------------------------------------------------
__global__ __launch_bounds__(256) void k_stats(
    const float* __restrict__ partials, float* __restrict__ stats)
{
  const int p = blockIdx.x;
  const int tid = threadIdx.x;
  float s1 = 0.f, s2 = 0.f;
  for (int i = tid; i < NBLK_ADD; i += 256) {
    s1 += partials[((size_t)p * NBLK_ADD + i) * 2 + 0];
    s2 += partials[((size_t)p * NBLK_ADD + i) * 2 + 1];
  }
  #pragma unroll
  for (int off = 32; off > 0; off >>= 1) {
    s1 += __shfl_down(s1, off);
    s2 += __shfl_down(s2, off);
  }
  __shared__ float red[8];
  int wid = tid >> 6, lane = tid & 63;
  if (lane == 0) { red[wid * 2] = s1; red[wid * 2 + 1] = s2; }
  __syncthreads();
  if (tid == 0) {
    float S1 = red[0] + red[2] + red[4] + red[6];
    float S2 = red[1] + red[3] + red[5] + red[7];
    float mean = S1 / (float)EN;
    float var = S2 / (float)EN - mean * mean;
    stats[p * 2 + 0] = mean;
    stats[p * 2 + 1] = rsqrtf(var + 1e-5f);
  }
}

// ---------------------------------------------------------------------------
// Kernel 3: apply LN-all elementwise.  Z layout == Y layout ([E,N] flat), which
// is exactly the [B,S,E]-layout view needed downstream (flat reinterpret).
// grid (591, 3) block 256, float4 per thread.
// ---------------------------------------------------------------------------
__global__ __launch_bounds__(256) void k_lnall(
    const float* __restrict__ Y, const float* __restrict__ stats,
    const float* __restrict__ w0, const float* __restrict__ b0,
    const float* __restrict__ w1, const float* __restrict__ b1,
    const float* __restrict__ w2, const float* __restrict__ b2,
    float* __restrict__ Z)
{
  const int p = blockIdx.y;
  const float* __restrict__ w = (p == 0) ? w0 : (p == 1) ? w1 : w2;
  const float* __restrict__ b = (p == 0) ? b0 : (p == 1) ? b1 : b2;
  const float mean = stats[p * 2 + 0];
  const float rstd = stats[p * 2 + 1];
  size_t i = ((size_t)blockIdx.x * 256 + threadIdx.x) * 4;
  const float* Yp = Y + (size_t)p * EN;
  float* Zp = Z + (size_t)p * EN;
  float4 y = *(const float4*)(Yp + i);
  float4 wv = *(const float4*)(w + i);
  float4 bv = *(const float4*)(b + i);
  float4 z;
  z.x = (y.x - mean) * rstd * wv.x + bv.x;
  z.y = (y.y - mean) * rstd * wv.y + bv.y;
  z.z = (y.z - mean) * rstd * wv.z + bv.z;
  z.w = (y.w - mean) * rstd * wv.w + bv.w;
  *(float4*)(Zp + i) = z;
}

// ---------------------------------------------------------------------------
// Kernel 4: QK^T.  att[bh][s][t] = scale * sum_d q[s,d]*k[t,d]
// q/k read strided from Z ([B,S,E] layout).  grid (48, 4, 4) block 256.
// ---------------------------------------------------------------------------
__global__ __launch_bounds__(256) void k_qk(
    const float* __restrict__ zq, const float* __restrict__ zk,
    float* __restrict__ att, float scale)
{
  const int bh = blockIdx.x, b = bh / H_, h = bh % H_;
  const int s0 = blockIdx.y * 64, t0 = blockIdx.z * 64;
  __shared__ float Qs[64][68];   // [d][s_local]
  __shared__ float Ks[64][68];   // [d][t_local]
  const int tid = threadIdx.x;
  {
    int rl = tid >> 4, c4 = (tid & 15) * 4;
    for (int rr = rl; rr < 64; rr += 16) {
      int s = s0 + rr;
      float4 v = make_float4(0.f, 0.f, 0.f, 0.f);
      if (s < S_) v = *(const float4*)(zq + (size_t)(b * S_ + s) * E_ + h * D_ + c4);
      Qs[c4 + 0][rr] = v.x; Qs[c4 + 1][rr] = v.y;
      Qs[c4 + 2][rr] = v.z; Qs[c4 + 3][rr] = v.w;
      int t = t0 + rr;
      float4 u = make_float4(0.f, 0.f, 0.f, 0.f);
      if (t < S_) u = *(const float4*)(zk + (size_t)(b * S_ + t) * E_ + h * D_ + c4);
      Ks[c4 + 0][rr] = u.x; Ks[c4 + 1][rr] = u.y;
      Ks[c4 + 2][rr] = u.z; Ks[c4 + 3][rr] = u.w;
    }
  }
  __syncthreads();
  const int r0 = (tid >> 4) * 4, c0 = (tid & 15) * 4;
  float acc[4][4];
  #pragma unroll
  for (int i = 0; i < 4; ++i)
    #pragma unroll
    for (int j = 0; j < 4; ++j) acc[i][j] = 0.f;
  #pragma unroll 8
  for (int d = 0; d < 64; ++d) {
    float4 q4 = *(const float4*)(&Qs[d][r0]);
    float4 k4 = *(const float4*)(&Ks[d][c0]);
    float qa[4] = {q4.x, q4.y, q4.z, q4.w};
    float ka[4] = {k4.x, k4.y, k4.z, k4.w};
    #pragma unroll
    for (int i = 0; i < 4; ++i)
      #pragma unroll
      for (int j = 0; j < 4; ++j)
        acc[i][j] += qa[i] * ka[j];
  }
  #pragma unroll
  for (int i = 0; i < 4; ++i) {
    int s = s0 + r0 + i;
    if (s < S_) {
      #pragma unroll
      for (int j = 0; j < 4; ++j) {
        int t = t0 + c0 + j;
        if (t < S_)
          att[((size_t)bh * S_ + s) * ATT_LD + t] = acc[i][j] * scale;
      }
    }
  }
}

// ---------------------------------------------------------------------------
// Kernel 5: row softmax + identity.  one wave per row. grid(2364) block 256.
// ---------------------------------------------------------------------------
__global__ __launch_bounds__(256) void k_softmax(float* __restrict__ att)
{
  const int row = blockIdx.x * 4 + (threadIdx.x >> 6);
  const int lane = threadIdx.x & 63;
  const int s = row % S_;
  float* base = att + (size_t)row * ATT_LD;
  float v[4];
  float m = -1e30f;
  #pragma unroll
  for (int j = 0; j < 4; ++j) {
    int t = lane + 64 * j;
    v[j] = (t < S_) ? base[t] : -1e30f;
    m = fmaxf(m, v[j]);
  }
  #pragma unroll
  for (int off = 32; off > 0; off >>= 1) m = fmaxf(m, __shfl_xor(m, off));
  float sum = 0.f;
  #pragma unroll
  for (int j = 0; j < 4; ++j) {
    int t = lane + 64 * j;
    v[j] = (t < S_) ? __expf(v[j] - m) : 0.f;
    sum += v[j];
  }
  #pragma unroll
  for (int off = 32; off > 0; off >>= 1) sum += __shfl_xor(sum, off);
  float inv = 1.f / sum;
  #pragma unroll
  for (int j = 0; j < 4; ++j) {
    int t = lane + 64 * j;
    if (t < S_) base[t] = v[j] * inv + ((t == s) ? 1.f : 0.f);
  }
}

// ---------------------------------------------------------------------------
// Kernel 6: PV.  o[bh][s][d] = sum_t att[s][t]*v[t][d]; written into [B,S,E]
// grid (48, 4) block 256.
// ---------------------------------------------------------------------------
__global__ __launch_bounds__(256) void k_pv(
    const float* __restrict__ att, const float* __restrict__ zv,
    float* __restrict__ obuf)
{
  const int bh = blockIdx.x, b = bh / H_, h = bh % H_;
  const int s0 = blockIdx.y * 64;
  __shared__ float As[64][68];   // [t_local][s_local] (transposed)
  __shared__ float Vs[64][68];   // [t_local][d]
  const int tid = threadIdx.x;
  const int r0 = (tid >> 4) * 4, d0 = (tid & 15) * 4;
  float acc[4][4];
  #pragma unroll
  for (int i = 0; i < 4; ++i)
    #pragma unroll
    for (int j = 0; j < 4; ++j) acc[i][j] = 0.f;

  for (int tt = 0; tt < 256; tt += 64) {
    {
      int sl = tid >> 4, t4 = (tid & 15) * 4;
      for (int rr = sl; rr < 64; rr += 16) {
        int s = s0 + rr;
        #pragma unroll
        for (int k = 0; k < 4; ++k) {
          int t = tt + t4 + k;
          float a = 0.f;
          if (s < S_ && t < S_) a = att[((size_t)bh * S_ + s) * ATT_LD + t];
          As[t4 + k][rr] = a;
        }
        int t = tt + rr;
        float4 v = make_float4(0.f, 0.f, 0.f, 0.f);
        if (t < S_) v = *(const float4*)(zv + (size_t)(b * S_ + t) * E_ + h * D_ + t4);
        *(float4*)(&Vs[rr][t4]) = v;
      }
    }
    __syncthreads();
    #pragma unroll 8
    for (int t = 0; t < 64; ++t) {
      float4 a4 = *(const float4*)(&As[t][r0]);
      float4 v4 = *(const float4*)(&Vs[t][d0]);
      float aa[4] = {a4.x, a4.y, a4.z, a4.w};
      float va[4] = {v4.x, v4.y, v4.z, v4.w};
      #pragma unroll
      for (int i = 0; i < 4; ++i)
        #pragma unroll
        for (int j = 0; j < 4; ++j)
          acc[i][j] += aa[i] * va[j];
    }
    __syncthreads();
  }
  #pragma unroll
  for (int i = 0; i < 4; ++i) {
    int s = s0 + r0 + i;
    if (s < S_) {
      float4 o = make_float4(acc[i][0], acc[i][1], acc[i][2], acc[i][3]);
      *(float4*)(obuf + (size_t)(b * S_ + s) * E_ + h * D_ + d0) = o;
    }
  }
}

// ---------------------------------------------------------------------------
// Kernel 7: LayerNorm over last dim (E) per token row. grid(394) block 256.
// ---------------------------------------------------------------------------
__global__ __launch_bounds__(256) void k_lnlast(
    const float* __restrict__ obuf,
    const float* __restrict__ lw, const float* __restrict__ lb,
    float* __restrict__ oln)
{
  const int row = blockIdx.x * 4 + (threadIdx.x >> 6);
  const int lane = threadIdx.x & 63;
  const float* base = obuf + (size_t)row * E_;
  float v[6];
  float s1 = 0.f;
  #pragma unroll
  for (int j = 0; j < 6; ++j) { v[j] = base[lane + 64 * j]; s1 += v[j]; }
  #pragma unroll
  for (int off = 32; off > 0; off >>= 1) s1 += __shfl_xor(s1, off);
  float mean = s1 * (1.f / E_);
  float s2 = 0.f;
  #pragma unroll
  for (int j = 0; j < 6; ++j) { float d = v[j] - mean; s2 += d * d; }
  #pragma unroll
  for (int off = 32; off > 0; off >>= 1) s2 += __shfl_xor(s2, off);
  float rstd = rsqrtf(s2 * (1.f / E_) + 1e-5f);
  float* ob = oln + (size_t)row * E_;
  #pragma unroll
  for (int j = 0; j < 6; ++j) {
    int e = lane + 64 * j;
    ob[e] = (v[j] - mean) * rstd * lw[e] + lb[e];
  }
}

// ---------------------------------------------------------------------------
// Kernel 8: final GEMM  out[n][j] = sum_e oln[n][e]*fcw[j][e] + fcb[j]
// grid (6, 25) block 256.
// ---------------------------------------------------------------------------
__global__ __launch_bounds__(256) void k_fc(
    const float* __restrict__ oln, const float* __restrict__ fcw,
    const float* __restrict__ fcb, float* __restrict__ out)
{
  const int j0 = blockIdx.x * 64, n0 = blockIdx.y * 64;
  __shared__ float Xs[16][64];   // [e][n]
  __shared__ float Ws[16][64];   // [e][j]
  const int tid = threadIdx.x;
  const int tx = tid & 15, ty = tid >> 4;
  float acc[4][4];
  #pragma unroll
  for (int i = 0; i < 4; ++i)
    #pragma unroll
    for (int j = 0; j < 4; ++j) acc[i][j] = 0.f;

  for (int e0 = 0; e0 < E_; e0 += 16) {
    {
      int nl = tid >> 2, c4 = (tid & 3) * 4;
      int n = n0 + nl;
      float4 v = make_float4(0.f, 0.f, 0.f, 0.f);
      if (n < N_) v = *(const float4*)(oln + (size_t)n * E_ + e0 + c4);
      Xs[c4 + 0][nl] = v.x; Xs[c4 + 1][nl] = v.y;
      Xs[c4 + 2][nl] = v.z; Xs[c4 + 3][nl] = v.w;
      float4 u = *(const float4*)(fcw + (size_t)(j0 + nl) * E_ + e0 + c4);
      Ws[c4 + 0][nl] = u.x; Ws[c4 + 1][nl] = u.y;
      Ws[c4 + 2][nl] = u.z; Ws[c4 + 3][nl] = u.w;
    }
    __syncthreads();
    #pragma unroll
    for (int cc = 0; cc < 16; ++cc) {
      float4 xv = *(const float4*)(&Xs[cc][tx * 4]);
      float4 wv4 = *(const float4*)(&Ws[cc][ty * 4]);
      float xa[4] = {xv.x, xv.y, xv.z, xv.w};
      float wa[4] = {wv4.x, wv4.y, wv4.z, wv4.w};
      #pragma unroll
      for (int i = 0; i < 4; ++i)
        #pragma unroll
        for (int j = 0; j < 4; ++j)
          acc[i][j] += wa[i] * xa[j];
    }
    __syncthreads();
  }
  #pragma unroll
  for (int jj = 0; jj < 4; ++jj) {
    int n = n0 + tx * 4 + jj;
    if (n < N_) {
      int jc = j0 + ty * 4;
      float4 o;
      o.x = acc[0][jj] + fcb[jc + 0];
      o.y = acc[1][jj] + fcb[jc + 1];
      o.z = acc[2][jj] + fcb[jc + 2];
      o.w = acc[3][jj] + fcb[jc + 3];
      *(float4*)(out + (size_t)n * E_ + jc) = o;
    }
  }
}

// ---------------------------------------------------------------------------
extern "C" void kernel_launch(void* const* d_in, const int* in_sizes, int n_in,
                              void* d_out, int out_size, void* d_ws, size_t ws_size,
                              hipStream_t stream)
{
  const float* x   = (const float*)d_in[0];
  const float* wq  = (const float*)d_in[1];
  const float* wk  = (const float*)d_in[2];
  const float* wv  = (const float*)d_in[3];
  const float* qw  = (const float*)d_in[4];
  const float* qb  = (const float*)d_in[5];
  const float* kw  = (const float*)d_in[6];
  const float* kb  = (const float*)d_in[7];
  const float* vw  = (const float*)d_in[8];
  const float* vb  = (const float*)d_in[9];
  const float* ow  = (const float*)d_in[10];
  const float* obp = (const float*)d_in[11];
  const float* fcw = (const float*)d_in[12];
  const float* fcb = (const float*)d_in[13];
  float* out = (float*)d_out;
  float* ws  = (float*)d_ws;

  float* Y     = ws;                                 // 3*EN
  float* Z     = Y + 3 * EN;                         // 3*EN
  float* att   = Z + 3 * EN;                         // 48*197*200
  float* obuf  = att + (size_t)48 * S_ * ATT_LD;     // EN
  float* oln   = obuf + EN;                          // EN
  float* part  = oln + EN;                           // 3*150*2
  float* stats = part + 3 * NBLK_ADD * 2;            // 6

  const float scale = (float)pow(2.0 * D_ * (1.0 - 2.0 / M_PI), -0.5);

  k_adder<<<dim3(6, 25, 3), 256, 0, stream>>>(x, wq, wk, wv, Y, part);
  k_stats<<<dim3(3), 256, 0, stream>>>(part, stats);
  k_lnall<<<dim3(591, 3), 256, 0, stream>>>(Y, stats, qw, qb, kw, kb, vw, vb, Z);
  const float* zq = Z;
  const float* zk = Z + EN;
  const float* zv = Z + 2 * EN;
  k_qk<<<dim3(48, 4, 4), 256, 0, stream>>>(zq, zk, att, scale);
  k_softmax<<<dim3(2364), 256, 0, stream>>>(att);
  k_pv<<<dim3(48, 4), 256, 0, stream>>>(att, zv, obuf);
  k_lnlast<<<dim3(394), 256, 0, stream>>>(obuf, ow, obp, oln);
  k_fc<<<dim3(6, 25), 256, 0, stream>>>(oln, fcw, fcb, out);
}

// Round 2
// 128.390 us; speedup vs baseline: 1.0178x; 1.0178x over previous
//
#include <hip/hip_runtime.h>
#include <math.h>

#ifndef M_PI
#define M_PI 3.14159265358979323846
#endif

#define B_ 8
#define S_ 197
#define E_ 384
#define H_ 6
#define D_ 64
#define N_ (B_*S_)          // 1576
#define EN ((size_t)E_*N_)  // 605184
#define ATT_LD 200
#define NBLK_ADD 300        // 6*50 blocks per projection

// ---------------------------------------------------------------------------
// Kernel 1: adder 1x1 for q,k,v.  Y[p][co][n] = -sum_ci |x2d[ci][n]-w[co][ci]|
// Tile 64co x 32n, thread = 4co x 2n.  grid (6, 50, 3) block 256.
// Register-prefetch pipeline: next tile's global loads issue before compute.
// Also emits per-block (sum, sumsq) partials for the LN-all stats.
// ---------------------------------------------------------------------------
__global__ __launch_bounds__(256) void k_adder(
    const float* __restrict__ x,
    const float* __restrict__ wq, const float* __restrict__ wk,
    const float* __restrict__ wv,
    float* __restrict__ Y, float* __restrict__ partials)
{
  const int p = blockIdx.z;
  const float* __restrict__ w = (p == 0) ? wq : (p == 1) ? wk : wv;
  const int co0 = blockIdx.x * 64;
  const int n0  = blockIdx.y * 32;

  __shared__ float Xs[16][32];   // [ci_local][n_local]
  __shared__ float Ws[16][64];   // [ci_local][co_local] (transposed)
  __shared__ float red[8];

  const int tid = threadIdx.x;
  const int tx = tid & 15;       // n direction (2 cols each)
  const int ty = tid >> 4;       // co direction (4 rows each)

  // staging coords
  const int xr = tid >> 4, xc = (tid & 15) * 2;   // X: [16][32], float2/thread
  const int wr = tid >> 2, wc = (tid & 3) * 4;    // W: 64co x 16ci, float4/thread

  const bool xok = (n0 + xc + 1) < N_;            // N_%2==0 -> all-or-none
  const float* xg = x + (size_t)xr * N_ + n0 + xc;
  const float* wg = w + (size_t)(co0 + wr) * E_ + wc;

  float2 xv = xok ? *(const float2*)xg : make_float2(0.f, 0.f);
  float4 wv4 = *(const float4*)wg;

  float acc[4][2];
  #pragma unroll
  for (int i = 0; i < 4; ++i) { acc[i][0] = 0.f; acc[i][1] = 0.f; }

  #pragma unroll 1
  for (int t = 0; t < 24; ++t) {
    if (t > 0) __syncthreads();          // previous tile fully consumed
    *(float2*)(&Xs[xr][xc]) = xv;
    Ws[wc + 0][wr] = wv4.x; Ws[wc + 1][wr] = wv4.y;
    Ws[wc + 2][wr] = wv4.z; Ws[wc + 3][wr] = wv4.w;
    __syncthreads();
    if (t < 23) {                        // prefetch next tile into registers
      xg += (size_t)16 * N_;
      wg += 16;
      xv = xok ? *(const float2*)xg : make_float2(0.f, 0.f);
      wv4 = *(const float4*)wg;
    }
    #pragma unroll
    for (int cc = 0; cc < 16; ++cc) {
      float2 x2 = *(const float2*)(&Xs[cc][tx * 2]);
      float4 w4 = *(const float4*)(&Ws[cc][ty * 4]);
      float xa[2] = {x2.x, x2.y};
      float wa[4] = {w4.x, w4.y, w4.z, w4.w};
      #pragma unroll
      for (int i = 0; i < 4; ++i)
        #pragma unroll
        for (int j = 0; j < 2; ++j)
          acc[i][j] += fabsf(xa[j] - wa[i]);
    }
  }

  float s1 = 0.f, s2 = 0.f;
  const int nb = n0 + tx * 2;
  if (nb + 1 < N_) {
    #pragma unroll
    for (int i = 0; i < 4; ++i) {
      int co = co0 + ty * 4 + i;
      float2 yv;
      yv.x = -acc[i][0]; yv.y = -acc[i][1];
      *(float2*)(Y + (size_t)p * EN + (size_t)co * N_ + nb) = yv;
      s1 += yv.x + yv.y;
      s2 += yv.x * yv.x + yv.y * yv.y;
    }
  }
  // block reduction of (s1, s2)
  #pragma unroll
  for (int off = 32; off > 0; off >>= 1) {
    s1 += __shfl_down(s1, off);
    s2 += __shfl_down(s2, off);
  }
  int wid = tid >> 6, lane = tid & 63;
  if (lane == 0) { red[wid * 2] = s1; red[wid * 2 + 1] = s2; }
  __syncthreads();
  if (tid == 0) {
    float t1 = red[0] + red[2] + red[4] + red[6];
    float t2 = red[1] + red[3] + red[5] + red[7];
    int blk = blockIdx.x * gridDim.y + blockIdx.y;
    partials[((size_t)p * NBLK_ADD + blk) * 2 + 0] = t1;
    partials[((size_t)p * NBLK_ADD + blk) * 2 + 1] = t2;
  }
}

// ---------------------------------------------------------------------------
// Kernel 2: reduce partials -> (mean, rstd) per projection.  grid(3) block 256
// ---------------------------------------------------------------------------
__global__ __launch_bounds__(256) void k_stats(
    const float* __restrict__ partials, float* __restrict__ stats)
{
  const int p = blockIdx.x;
  const int tid = threadIdx.x;
  float s1 = 0.f, s2 = 0.f;
  for (int i = tid; i < NBLK_ADD; i += 256) {
    s1 += partials[((size_t)p * NBLK_ADD + i) * 2 + 0];
    s2 += partials[((size_t)p * NBLK_ADD + i) * 2 + 1];
  }
  #pragma unroll
  for (int off = 32; off > 0; off >>= 1) {
    s1 += __shfl_down(s1, off);
    s2 += __shfl_down(s2, off);
  }
  __shared__ float red[8];
  int wid = tid >> 6, lane = tid & 63;
  if (lane == 0) { red[wid * 2] = s1; red[wid * 2 + 1] = s2; }
  __syncthreads();
  if (tid == 0) {
    float S1 = red[0] + red[2] + red[4] + red[6];
    float S2 = red[1] + red[3] + red[5] + red[7];
    float mean = S1 / (float)EN;
    float var = S2 / (float)EN - mean * mean;
    stats[p * 2 + 0] = mean;
    stats[p * 2 + 1] = rsqrtf(var + 1e-5f);
  }
}

// ---------------------------------------------------------------------------
// Kernel 3: apply LN-all elementwise.  Z layout == Y layout ([E,N] flat), which
// is exactly the [B,S,E]-layout view needed downstream (flat reinterpret).
// grid (591, 3) block 256, float4 per thread.
// ---------------------------------------------------------------------------
__global__ __launch_bounds__(256) void k_lnall(
    const float* __restrict__ Y, const float* __restrict__ stats,
    const float* __restrict__ w0, const float* __restrict__ b0,
    const float* __restrict__ w1, const float* __restrict__ b1,
    const float* __restrict__ w2, const float* __restrict__ b2,
    float* __restrict__ Z)
{
  const int p = blockIdx.y;
  const float* __restrict__ w = (p == 0) ? w0 : (p == 1) ? w1 : w2;
  const float* __restrict__ b = (p == 0) ? b0 : (p == 1) ? b1 : b2;
  const float mean = stats[p * 2 + 0];
  const float rstd = stats[p * 2 + 1];
  size_t i = ((size_t)blockIdx.x * 256 + threadIdx.x) * 4;
  const float* Yp = Y + (size_t)p * EN;
  float* Zp = Z + (size_t)p * EN;
  float4 y = *(const float4*)(Yp + i);
  float4 wv = *(const float4*)(w + i);
  float4 bv = *(const float4*)(b + i);
  float4 z;
  z.x = (y.x - mean) * rstd * wv.x + bv.x;
  z.y = (y.y - mean) * rstd * wv.y + bv.y;
  z.z = (y.z - mean) * rstd * wv.z + bv.z;
  z.w = (y.w - mean) * rstd * wv.w + bv.w;
  *(float4*)(Zp + i) = z;
}

// ---------------------------------------------------------------------------
// Kernel 4: QK^T.  att[bh][s][t] = scale * sum_d q[s,d]*k[t,d]
// q/k read strided from Z ([B,S,E] layout).  grid (48, 4, 4) block 256.
// ---------------------------------------------------------------------------
__global__ __launch_bounds__(256) void k_qk(
    const float* __restrict__ zq, const float* __restrict__ zk,
    float* __restrict__ att, float scale)
{
  const int bh = blockIdx.x, b = bh / H_, h = bh % H_;
  const int s0 = blockIdx.y * 64, t0 = blockIdx.z * 64;
  __shared__ float Qs[64][68];   // [d][s_local]
  __shared__ float Ks[64][68];   // [d][t_local]
  const int tid = threadIdx.x;
  {
    int rl = tid >> 4, c4 = (tid & 15) * 4;
    for (int rr = rl; rr < 64; rr += 16) {
      int s = s0 + rr;
      float4 v = make_float4(0.f, 0.f, 0.f, 0.f);
      if (s < S_) v = *(const float4*)(zq + (size_t)(b * S_ + s) * E_ + h * D_ + c4);
      Qs[c4 + 0][rr] = v.x; Qs[c4 + 1][rr] = v.y;
      Qs[c4 + 2][rr] = v.z; Qs[c4 + 3][rr] = v.w;
      int t = t0 + rr;
      float4 u = make_float4(0.f, 0.f, 0.f, 0.f);
      if (t < S_) u = *(const float4*)(zk + (size_t)(b * S_ + t) * E_ + h * D_ + c4);
      Ks[c4 + 0][rr] = u.x; Ks[c4 + 1][rr] = u.y;
      Ks[c4 + 2][rr] = u.z; Ks[c4 + 3][rr] = u.w;
    }
  }
  __syncthreads();
  const int r0 = (tid >> 4) * 4, c0 = (tid & 15) * 4;
  float acc[4][4];
  #pragma unroll
  for (int i = 0; i < 4; ++i)
    #pragma unroll
    for (int j = 0; j < 4; ++j) acc[i][j] = 0.f;
  #pragma unroll 8
  for (int d = 0; d < 64; ++d) {
    float4 q4 = *(const float4*)(&Qs[d][r0]);
    float4 k4 = *(const float4*)(&Ks[d][c0]);
    float qa[4] = {q4.x, q4.y, q4.z, q4.w};
    float ka[4] = {k4.x, k4.y, k4.z, k4.w};
    #pragma unroll
    for (int i = 0; i < 4; ++i)
      #pragma unroll
      for (int j = 0; j < 4; ++j)
        acc[i][j] += qa[i] * ka[j];
  }
  #pragma unroll
  for (int i = 0; i < 4; ++i) {
    int s = s0 + r0 + i;
    if (s < S_) {
      #pragma unroll
      for (int j = 0; j < 4; ++j) {
        int t = t0 + c0 + j;
        if (t < S_)
          att[((size_t)bh * S_ + s) * ATT_LD + t] = acc[i][j] * scale;
      }
    }
  }
}

// ---------------------------------------------------------------------------
// Kernel 5: row softmax + identity.  one wave per row. grid(2364) block 256.
// ---------------------------------------------------------------------------
__global__ __launch_bounds__(256) void k_softmax(float* __restrict__ att)
{
  const int row = blockIdx.x * 4 + (threadIdx.x >> 6);
  const int lane = threadIdx.x & 63;
  const int s = row % S_;
  float* base = att + (size_t)row * ATT_LD;
  float v[4];
  float m = -1e30f;
  #pragma unroll
  for (int j = 0; j < 4; ++j) {
    int t = lane + 64 * j;
    v[j] = (t < S_) ? base[t] : -1e30f;
    m = fmaxf(m, v[j]);
  }
  #pragma unroll
  for (int off = 32; off > 0; off >>= 1) m = fmaxf(m, __shfl_xor(m, off));
  float sum = 0.f;
  #pragma unroll
  for (int j = 0; j < 4; ++j) {
    int t = lane + 64 * j;
    v[j] = (t < S_) ? __expf(v[j] - m) : 0.f;
    sum += v[j];
  }
  #pragma unroll
  for (int off = 32; off > 0; off >>= 1) sum += __shfl_xor(sum, off);
  float inv = 1.f / sum;
  #pragma unroll
  for (int j = 0; j < 4; ++j) {
    int t = lane + 64 * j;
    if (t < S_) base[t] = v[j] * inv + ((t == s) ? 1.f : 0.f);
  }
}

// ---------------------------------------------------------------------------
// Kernel 6: PV.  o[bh][s][d] = sum_t att[s][t]*v[t][d]; written into [B,S,E]
// grid (48, 4) block 256.
// ---------------------------------------------------------------------------
__global__ __launch_bounds__(256) void k_pv(
    const float* __restrict__ att, const float* __restrict__ zv,
    float* __restrict__ obuf)
{
  const int bh = blockIdx.x, b = bh / H_, h = bh % H_;
  const int s0 = blockIdx.y * 64;
  __shared__ float As[64][68];   // [t_local][s_local] (transposed)
  __shared__ float Vs[64][68];   // [t_local][d]
  const int tid = threadIdx.x;
  const int r0 = (tid >> 4) * 4, d0 = (tid & 15) * 4;
  float acc[4][4];
  #pragma unroll
  for (int i = 0; i < 4; ++i)
    #pragma unroll
    for (int j = 0; j < 4; ++j) acc[i][j] = 0.f;

  for (int tt = 0; tt < 256; tt += 64) {
    {
      int sl = tid >> 4, t4 = (tid & 15) * 4;
      for (int rr = sl; rr < 64; rr += 16) {
        int s = s0 + rr;
        #pragma unroll
        for (int k = 0; k < 4; ++k) {
          int t = tt + t4 + k;
          float a = 0.f;
          if (s < S_ && t < S_) a = att[((size_t)bh * S_ + s) * ATT_LD + t];
          As[t4 + k][rr] = a;
        }
        int t = tt + rr;
        float4 v = make_float4(0.f, 0.f, 0.f, 0.f);
        if (t < S_) v = *(const float4*)(zv + (size_t)(b * S_ + t) * E_ + h * D_ + t4);
        *(float4*)(&Vs[rr][t4]) = v;
      }
    }
    __syncthreads();
    #pragma unroll 8
    for (int t = 0; t < 64; ++t) {
      float4 a4 = *(const float4*)(&As[t][r0]);
      float4 v4 = *(const float4*)(&Vs[t][d0]);
      float aa[4] = {a4.x, a4.y, a4.z, a4.w};
      float va[4] = {v4.x, v4.y, v4.z, v4.w};
      #pragma unroll
      for (int i = 0; i < 4; ++i)
        #pragma unroll
        for (int j = 0; j < 4; ++j)
          acc[i][j] += aa[i] * va[j];
    }
    __syncthreads();
  }
  #pragma unroll
  for (int i = 0; i < 4; ++i) {
    int s = s0 + r0 + i;
    if (s < S_) {
      float4 o = make_float4(acc[i][0], acc[i][1], acc[i][2], acc[i][3]);
      *(float4*)(obuf + (size_t)(b * S_ + s) * E_ + h * D_ + d0) = o;
    }
  }
}

// ---------------------------------------------------------------------------
// Kernel 7: LayerNorm over last dim (E) per token row. grid(394) block 256.
// ---------------------------------------------------------------------------
__global__ __launch_bounds__(256) void k_lnlast(
    const float* __restrict__ obuf,
    const float* __restrict__ lw, const float* __restrict__ lb,
    float* __restrict__ oln)
{
  const int row = blockIdx.x * 4 + (threadIdx.x >> 6);
  const int lane = threadIdx.x & 63;
  const float* base = obuf + (size_t)row * E_;
  float v[6];
  float s1 = 0.f;
  #pragma unroll
  for (int j = 0; j < 6; ++j) { v[j] = base[lane + 64 * j]; s1 += v[j]; }
  #pragma unroll
  for (int off = 32; off > 0; off >>= 1) s1 += __shfl_xor(s1, off);
  float mean = s1 * (1.f / E_);
  float s2 = 0.f;
  #pragma unroll
  for (int j = 0; j < 6; ++j) { float d = v[j] - mean; s2 += d * d; }
  #pragma unroll
  for (int off = 32; off > 0; off >>= 1) s2 += __shfl_xor(s2, off);
  float rstd = rsqrtf(s2 * (1.f / E_) + 1e-5f);
  float* ob = oln + (size_t)row * E_;
  #pragma unroll
  for (int j = 0; j < 6; ++j) {
    int e = lane + 64 * j;
    ob[e] = (v[j] - mean) * rstd * lw[e] + lb[e];
  }
}

// ---------------------------------------------------------------------------
// Kernel 8: final GEMM  out[n][j] = sum_e oln[n][e]*fcw[j][e] + fcb[j]
// grid (6, 25) block 256.
// ---------------------------------------------------------------------------
__global__ __launch_bounds__(256) void k_fc(
    const float* __restrict__ oln, const float* __restrict__ fcw,
    const float* __restrict__ fcb, float* __restrict__ out)
{
  const int j0 = blockIdx.x * 64, n0 = blockIdx.y * 64;
  __shared__ float Xs[16][64];   // [e][n]
  __shared__ float Ws[16][64];   // [e][j]
  const int tid = threadIdx.x;
  const int tx = tid & 15, ty = tid >> 4;
  float acc[4][4];
  #pragma unroll
  for (int i = 0; i < 4; ++i)
    #pragma unroll
    for (int j = 0; j < 4; ++j) acc[i][j] = 0.f;

  for (int e0 = 0; e0 < E_; e0 += 16) {
    {
      int nl = tid >> 2, c4 = (tid & 3) * 4;
      int n = n0 + nl;
      float4 v = make_float4(0.f, 0.f, 0.f, 0.f);
      if (n < N_) v = *(const float4*)(oln + (size_t)n * E_ + e0 + c4);
      Xs[c4 + 0][nl] = v.x; Xs[c4 + 1][nl] = v.y;
      Xs[c4 + 2][nl] = v.z; Xs[c4 + 3][nl] = v.w;
      float4 u = *(const float4*)(fcw + (size_t)(j0 + nl) * E_ + e0 + c4);
      Ws[c4 + 0][nl] = u.x; Ws[c4 + 1][nl] = u.y;
      Ws[c4 + 2][nl] = u.z; Ws[c4 + 3][nl] = u.w;
    }
    __syncthreads();
    #pragma unroll
    for (int cc = 0; cc < 16; ++cc) {
      float4 xv = *(const float4*)(&Xs[cc][tx * 4]);
      float4 wv4 = *(const float4*)(&Ws[cc][ty * 4]);
      float xa[4] = {xv.x, xv.y, xv.z, xv.w};
      float wa[4] = {wv4.x, wv4.y, wv4.z, wv4.w};
      #pragma unroll
      for (int i = 0; i < 4; ++i)
        #pragma unroll
        for (int j = 0; j < 4; ++j)
          acc[i][j] += wa[i] * xa[j];
    }
    __syncthreads();
  }
  #pragma unroll
  for (int jj = 0; jj < 4; ++jj) {
    int n = n0 + tx * 4 + jj;
    if (n < N_) {
      int jc = j0 + ty * 4;
      float4 o;
      o.x = acc[0][jj] + fcb[jc + 0];
      o.y = acc[1][jj] + fcb[jc + 1];
      o.z = acc[2][jj] + fcb[jc + 2];
      o.w = acc[3][jj] + fcb[jc + 3];
      *(float4*)(out + (size_t)n * E_ + jc) = o;
    }
  }
}

// ---------------------------------------------------------------------------
extern "C" void kernel_launch(void* const* d_in, const int* in_sizes, int n_in,
                              void* d_out, int out_size, void* d_ws, size_t ws_size,
                              hipStream_t stream)
{
  const float* x   = (const float*)d_in[0];
  const float* wq  = (const float*)d_in[1];
  const float* wk  = (const float*)d_in[2];
  const float* wv  = (const float*)d_in[3];
  const float* qw  = (const float*)d_in[4];
  const float* qb  = (const float*)d_in[5];
  const float* kw  = (const float*)d_in[6];
  const float* kb  = (const float*)d_in[7];
  const float* vw  = (const float*)d_in[8];
  const float* vb  = (const float*)d_in[9];
  const float* ow  = (const float*)d_in[10];
  const float* obp = (const float*)d_in[11];
  const float* fcw = (const float*)d_in[12];
  const float* fcb = (const float*)d_in[13];
  float* out = (float*)d_out;
  float* ws  = (float*)d_ws;

  float* Y     = ws;                                 // 3*EN
  float* Z     = Y + 3 * EN;                         // 3*EN
  float* att   = Z + 3 * EN;                         // 48*197*200
  float* obuf  = att + (size_t)48 * S_ * ATT_LD;     // EN
  float* oln   = obuf + EN;                          // EN
  float* part  = oln + EN;                           // 3*300*2
  float* stats = part + 3 * NBLK_ADD * 2;            // 6

  const float scale = (float)pow(2.0 * D_ * (1.0 - 2.0 / M_PI), -0.5);

  k_adder<<<dim3(6, 50, 3), 256, 0, stream>>>(x, wq, wk, wv, Y, part);
  k_stats<<<dim3(3), 256, 0, stream>>>(part, stats);
  k_lnall<<<dim3(591, 3), 256, 0, stream>>>(Y, stats, qw, qb, kw, kb, vw, vb, Z);
  const float* zq = Z;
  const float* zk = Z + EN;
  const float* zv = Z + 2 * EN;
  k_qk<<<dim3(48, 4, 4), 256, 0, stream>>>(zq, zk, att, scale);
  k_softmax<<<dim3(2364), 256, 0, stream>>>(att);
  k_pv<<<dim3(48, 4), 256, 0, stream>>>(att, zv, obuf);
  k_lnlast<<<dim3(394), 256, 0, stream>>>(obuf, ow, obp, oln);
  k_fc<<<dim3(6, 25), 256, 0, stream>>>(oln, fcw, fcb, out);
}

// Round 3
// 114.586 us; speedup vs baseline: 1.1404x; 1.1205x over previous
//
#include <hip/hip_runtime.h>
#include <math.h>

#ifndef M_PI
#define M_PI 3.14159265358979323846
#endif

#define B_ 8
#define S_ 197
#define E_ 384
#define H_ 6
#define D_ 64
#define N_ (B_*S_)          // 1576
#define EN ((size_t)E_*N_)  // 605184
#define NBLK_RED 591        // EN / 1024 exactly

// ---------------------------------------------------------------------------
// Kernel 1: adder 1x1 partials, split-K over ci (2 chunks of 192).
// P[z][co][n] = sum_{ci in chunk} |x2d[ci][n] - w[co][ci]|,  z = 2p + c.
// Tile 64co x 32n, thread = 4co x 2n.  grid (6, 50, 6) block 256.
// ---------------------------------------------------------------------------
__global__ __launch_bounds__(256) void k_adder(
    const float* __restrict__ x,
    const float* __restrict__ wq, const float* __restrict__ wk,
    const float* __restrict__ wv,
    float* __restrict__ P)
{
  const int z = blockIdx.z;
  const int p = z >> 1, c = z & 1;
  const float* __restrict__ w = (p == 0) ? wq : (p == 1) ? wk : wv;
  const int co0 = blockIdx.x * 64;
  const int n0  = blockIdx.y * 32;
  const int cib = c * 192;

  __shared__ float Xs[16][32];   // [ci_local][n_local]
  __shared__ float Ws[16][64];   // [ci_local][co_local] (transposed)

  const int tid = threadIdx.x;
  const int tx = tid & 15;       // n direction (2 cols each)
  const int ty = tid >> 4;       // co direction (4 rows each)

  const int xr = tid >> 4, xc = (tid & 15) * 2;   // X: [16][32], float2/thread
  const int wr = tid >> 2, wc = (tid & 3) * 4;    // W: 64co x 16ci, float4/thread

  const bool xok = (n0 + xc + 1) < N_;            // N_%2==0 -> all-or-none
  const float* xg = x + (size_t)(cib + xr) * N_ + n0 + xc;
  const float* wg = w + (size_t)(co0 + wr) * E_ + cib + wc;

  float2 xv = xok ? *(const float2*)xg : make_float2(0.f, 0.f);
  float4 wv4 = *(const float4*)wg;

  float acc[4][2];
  #pragma unroll
  for (int i = 0; i < 4; ++i) { acc[i][0] = 0.f; acc[i][1] = 0.f; }

  #pragma unroll 1
  for (int t = 0; t < 12; ++t) {
    if (t > 0) __syncthreads();
    *(float2*)(&Xs[xr][xc]) = xv;
    Ws[wc + 0][wr] = wv4.x; Ws[wc + 1][wr] = wv4.y;
    Ws[wc + 2][wr] = wv4.z; Ws[wc + 3][wr] = wv4.w;
    __syncthreads();
    if (t < 11) {
      xg += (size_t)16 * N_;
      wg += 16;
      xv = xok ? *(const float2*)xg : make_float2(0.f, 0.f);
      wv4 = *(const float4*)wg;
    }
    #pragma unroll
    for (int cc = 0; cc < 16; ++cc) {
      float2 x2 = *(const float2*)(&Xs[cc][tx * 2]);
      float4 w4 = *(const float4*)(&Ws[cc][ty * 4]);
      float xa[2] = {x2.x, x2.y};
      float wa[4] = {w4.x, w4.y, w4.z, w4.w};
      #pragma unroll
      for (int i = 0; i < 4; ++i)
        #pragma unroll
        for (int j = 0; j < 2; ++j)
          acc[i][j] += fabsf(xa[j] - wa[i]);
    }
  }

  const int nb = n0 + tx * 2;
  if (nb + 1 < N_) {
    #pragma unroll
    for (int i = 0; i < 4; ++i) {
      int co = co0 + ty * 4 + i;
      float2 yv; yv.x = acc[i][0]; yv.y = acc[i][1];
      *(float2*)(P + (size_t)z * EN + (size_t)co * N_ + nb) = yv;
    }
  }
}

// ---------------------------------------------------------------------------
// Kernel 2: reduce split-K partials in place: Y(=slot 2p) = -(P0+P1),
// plus per-block (sum, sumsq) partials for LN-all.  grid (591, 3) block 256.
// ---------------------------------------------------------------------------
__global__ __launch_bounds__(256) void k_reduceY(
    float* __restrict__ wsbuf, float* __restrict__ partials)
{
  const int p = blockIdx.y;
  float* P0 = wsbuf + (size_t)(2 * p) * EN;
  const float* P1 = wsbuf + (size_t)(2 * p + 1) * EN;
  const int tid = threadIdx.x;
  size_t i = ((size_t)blockIdx.x * 256 + tid) * 4;
  float4 a = *(const float4*)(P0 + i);
  float4 b = *(const float4*)(P1 + i);
  float4 y;
  y.x = -(a.x + b.x); y.y = -(a.y + b.y);
  y.z = -(a.z + b.z); y.w = -(a.w + b.w);
  *(float4*)(P0 + i) = y;
  float s1 = y.x + y.y + y.z + y.w;
  float s2 = y.x * y.x + y.y * y.y + y.z * y.z + y.w * y.w;
  #pragma unroll
  for (int off = 32; off > 0; off >>= 1) {
    s1 += __shfl_down(s1, off);
    s2 += __shfl_down(s2, off);
  }
  __shared__ float red[8];
  int wid = tid >> 6, lane = tid & 63;
  if (lane == 0) { red[wid * 2] = s1; red[wid * 2 + 1] = s2; }
  __syncthreads();
  if (tid == 0) {
    float t1 = red[0] + red[2] + red[4] + red[6];
    float t2 = red[1] + red[3] + red[5] + red[7];
    partials[((size_t)p * NBLK_RED + blockIdx.x) * 2 + 0] = t1;
    partials[((size_t)p * NBLK_RED + blockIdx.x) * 2 + 1] = t2;
  }
}

// ---------------------------------------------------------------------------
// Kernel 3: reduce partials -> (mean, rstd) per projection.  grid(3) block 256
// ---------------------------------------------------------------------------
__global__ __launch_bounds__(256) void k_stats(
    const float* __restrict__ partials, float* __restrict__ stats)
{
  const int p = blockIdx.x;
  const int tid = threadIdx.x;
  float s1 = 0.f, s2 = 0.f;
  for (int i = tid; i < NBLK_RED; i += 256) {
    s1 += partials[((size_t)p * NBLK_RED + i) * 2 + 0];
    s2 += partials[((size_t)p * NBLK_RED + i) * 2 + 1];
  }
  #pragma unroll
  for (int off = 32; off > 0; off >>= 1) {
    s1 += __shfl_down(s1, off);
    s2 += __shfl_down(s2, off);
  }
  __shared__ float red[8];
  int wid = tid >> 6, lane = tid & 63;
  if (lane == 0) { red[wid * 2] = s1; red[wid * 2 + 1] = s2; }
  __syncthreads();
  if (tid == 0) {
    float S1 = red[0] + red[2] + red[4] + red[6];
    float S2 = red[1] + red[3] + red[5] + red[7];
    float mean = S1 / (float)EN;
    float var = S2 / (float)EN - mean * mean;
    stats[p * 2 + 0] = mean;
    stats[p * 2 + 1] = rsqrtf(var + 1e-5f);
  }
}

// ---------------------------------------------------------------------------
// Kernel 4: apply LN-all elementwise.  Y in slot 2p, Z written to slot 2p+1
// (dead partial buffer).  grid (591, 3) block 256, float4 per thread.
// ---------------------------------------------------------------------------
__global__ __launch_bounds__(256) void k_lnall(
    float* __restrict__ wsbuf, const float* __restrict__ stats,
    const float* __restrict__ w0, const float* __restrict__ b0,
    const float* __restrict__ w1, const float* __restrict__ b1,
    const float* __restrict__ w2, const float* __restrict__ b2)
{
  const int p = blockIdx.y;
  const float* __restrict__ w = (p == 0) ? w0 : (p == 1) ? w1 : w2;
  const float* __restrict__ b = (p == 0) ? b0 : (p == 1) ? b1 : b2;
  const float mean = stats[p * 2 + 0];
  const float rstd = stats[p * 2 + 1];
  size_t i = ((size_t)blockIdx.x * 256 + threadIdx.x) * 4;
  const float* Yp = wsbuf + (size_t)(2 * p) * EN;
  float* Zp = wsbuf + (size_t)(2 * p + 1) * EN;
  float4 y = *(const float4*)(Yp + i);
  float4 wv = *(const float4*)(w + i);
  float4 bv = *(const float4*)(b + i);
  float4 z;
  z.x = (y.x - mean) * rstd * wv.x + bv.x;
  z.y = (y.y - mean) * rstd * wv.y + bv.y;
  z.z = (y.z - mean) * rstd * wv.z + bv.z;
  z.w = (y.w - mean) * rstd * wv.w + bv.w;
  *(float4*)(Zp + i) = z;
}

// ---------------------------------------------------------------------------
// Kernel 5: fused attention: scores + softmax + (P+I)V  per (bh, 32-row tile).
// grid (48, 7) block 256.  O += V[s] folds the +eye(S).
// ---------------------------------------------------------------------------
__global__ __launch_bounds__(256) void k_attn(
    const float* __restrict__ zq, const float* __restrict__ zk,
    const float* __restrict__ zv, float* __restrict__ obuf, float scale)
{
  const int bh = blockIdx.x, b = bh / H_, h = bh % H_;
  const int s0 = blockIdx.y * 32;

  __shared__ float Qs[64][36];    // [d][s_local]
  __shared__ float KVs[64][68];   // K phase: [d][t_local]; V phase: [t_local][d]
  __shared__ float Ps[32][200];   // normalized-unscaled exp scores
  __shared__ float linv[32];

  const int tid = threadIdx.x;
  const int tx = tid & 15, ty = tid >> 4;

  // stage Q: 32 rows x 64 d -> Qs[d][s]
  #pragma unroll
  for (int it = 0; it < 2; ++it) {
    int idx = tid + it * 256;
    int sl = idx >> 4, c4 = (idx & 15) * 4;
    int s = s0 + sl;
    float4 v = make_float4(0.f, 0.f, 0.f, 0.f);
    if (s < S_) v = *(const float4*)(zq + (size_t)(b * S_ + s) * E_ + h * D_ + c4);
    Qs[c4 + 0][sl] = v.x; Qs[c4 + 1][sl] = v.y;
    Qs[c4 + 2][sl] = v.z; Qs[c4 + 3][sl] = v.w;
  }

  float accS[4][2][4];
  #pragma unroll
  for (int tt = 0; tt < 4; ++tt)
    #pragma unroll
    for (int r = 0; r < 2; ++r)
      #pragma unroll
      for (int j = 0; j < 4; ++j) accS[tt][r][j] = 0.f;

  #pragma unroll
  for (int tt = 0; tt < 4; ++tt) {
    __syncthreads();   // previous KVs consumers done (also covers Qs staging)
    #pragma unroll
    for (int it = 0; it < 4; ++it) {
      int idx = tid + it * 256;
      int tl = idx >> 4, c4 = (idx & 15) * 4;
      int t = tt * 64 + tl;
      float4 u = make_float4(0.f, 0.f, 0.f, 0.f);
      if (t < S_) u = *(const float4*)(zk + (size_t)(b * S_ + t) * E_ + h * D_ + c4);
      KVs[c4 + 0][tl] = u.x; KVs[c4 + 1][tl] = u.y;
      KVs[c4 + 2][tl] = u.z; KVs[c4 + 3][tl] = u.w;
    }
    __syncthreads();
    #pragma unroll 8
    for (int d = 0; d < 64; ++d) {
      float2 q2 = *(const float2*)(&Qs[d][2 * ty]);
      float4 k4 = *(const float4*)(&KVs[d][tx * 4]);
      float ka[4] = {k4.x, k4.y, k4.z, k4.w};
      #pragma unroll
      for (int j = 0; j < 4; ++j) {
        accS[tt][0][j] += q2.x * ka[j];
        accS[tt][1][j] += q2.y * ka[j];
      }
    }
  }

  // row softmax over full 197 (rows 2ty, 2ty+1; cols spread over 16 tx lanes)
  float mr0 = -1e30f, mr1 = -1e30f;
  #pragma unroll
  for (int tt = 0; tt < 4; ++tt)
    #pragma unroll
    for (int j = 0; j < 4; ++j) {
      int t = tt * 64 + tx * 4 + j;
      float v0 = (t < S_) ? accS[tt][0][j] * scale : -1e30f;
      float v1 = (t < S_) ? accS[tt][1][j] * scale : -1e30f;
      accS[tt][0][j] = v0; accS[tt][1][j] = v1;
      mr0 = fmaxf(mr0, v0); mr1 = fmaxf(mr1, v1);
    }
  #pragma unroll
  for (int off = 1; off < 16; off <<= 1) {
    mr0 = fmaxf(mr0, __shfl_xor(mr0, off));
    mr1 = fmaxf(mr1, __shfl_xor(mr1, off));
  }
  float sr0 = 0.f, sr1 = 0.f;
  #pragma unroll
  for (int tt = 0; tt < 4; ++tt)
    #pragma unroll
    for (int j = 0; j < 4; ++j) {
      float p0 = __expf(accS[tt][0][j] - mr0);
      float p1 = __expf(accS[tt][1][j] - mr1);
      accS[tt][0][j] = p0; accS[tt][1][j] = p1;
      sr0 += p0; sr1 += p1;
    }
  #pragma unroll
  for (int off = 1; off < 16; off <<= 1) {
    sr0 += __shfl_xor(sr0, off);
    sr1 += __shfl_xor(sr1, off);
  }
  if (tx == 0) { linv[2 * ty] = 1.f / sr0; linv[2 * ty + 1] = 1.f / sr1; }
  #pragma unroll
  for (int tt = 0; tt < 4; ++tt) {
    int t4 = tt * 64 + tx * 4;
    if (t4 < 200) {
      *(float4*)(&Ps[2 * ty][t4]) =
          make_float4(accS[tt][0][0], accS[tt][0][1], accS[tt][0][2], accS[tt][0][3]);
      *(float4*)(&Ps[2 * ty + 1][t4]) =
          make_float4(accS[tt][1][0], accS[tt][1][1], accS[tt][1][2], accS[tt][1][3]);
    }
  }

  // PV phase: O[2 rows][4 d] per thread
  float accO[2][4];
  #pragma unroll
  for (int r = 0; r < 2; ++r)
    #pragma unroll
    for (int j = 0; j < 4; ++j) accO[r][j] = 0.f;

  #pragma unroll
  for (int tt = 0; tt < 4; ++tt) {
    __syncthreads();   // S-phase/previous-PV KVs reads done; Ps visible (tt=0)
    #pragma unroll
    for (int it = 0; it < 4; ++it) {
      int idx = tid + it * 256;
      int tl = idx >> 4, c4 = (idx & 15) * 4;
      int t = tt * 64 + tl;
      float4 u = make_float4(0.f, 0.f, 0.f, 0.f);
      if (t < S_) u = *(const float4*)(zv + (size_t)(b * S_ + t) * E_ + h * D_ + c4);
      *(float4*)(&KVs[tl][c4]) = u;
    }
    __syncthreads();
    const int tmax = (tt < 3) ? 64 : 8;   // Ps cols < 200
    #pragma unroll 8
    for (int tl = 0; tl < tmax; ++tl) {
      float p0 = Ps[2 * ty][tt * 64 + tl];
      float p1 = Ps[2 * ty + 1][tt * 64 + tl];
      float4 v4 = *(const float4*)(&KVs[tl][tx * 4]);
      float va[4] = {v4.x, v4.y, v4.z, v4.w};
      #pragma unroll
      for (int j = 0; j < 4; ++j) {
        accO[0][j] += p0 * va[j];
        accO[1][j] += p1 * va[j];
      }
    }
  }

  // epilogue: O = O*inv + V[s]  (identity fold), store to obuf [B,S,E]
  #pragma unroll
  for (int r = 0; r < 2; ++r) {
    int s = s0 + 2 * ty + r;
    if (s < S_) {
      float inv = linv[2 * ty + r];
      float4 vs = *(const float4*)(zv + (size_t)(b * S_ + s) * E_ + h * D_ + tx * 4);
      float4 o;
      o.x = accO[r][0] * inv + vs.x;
      o.y = accO[r][1] * inv + vs.y;
      o.z = accO[r][2] * inv + vs.z;
      o.w = accO[r][3] * inv + vs.w;
      *(float4*)(obuf + (size_t)(b * S_ + s) * E_ + h * D_ + tx * 4) = o;
    }
  }
}

// ---------------------------------------------------------------------------
// Kernel 6: LayerNorm over last dim (E) per token row. grid(394) block 256.
// ---------------------------------------------------------------------------
__global__ __launch_bounds__(256) void k_lnlast(
    const float* __restrict__ obuf,
    const float* __restrict__ lw, const float* __restrict__ lb,
    float* __restrict__ oln)
{
  const int row = blockIdx.x * 4 + (threadIdx.x >> 6);
  const int lane = threadIdx.x & 63;
  const float* base = obuf + (size_t)row * E_;
  float v[6];
  float s1 = 0.f;
  #pragma unroll
  for (int j = 0; j < 6; ++j) { v[j] = base[lane + 64 * j]; s1 += v[j]; }
  #pragma unroll
  for (int off = 32; off > 0; off >>= 1) s1 += __shfl_xor(s1, off);
  float mean = s1 * (1.f / E_);
  float s2 = 0.f;
  #pragma unroll
  for (int j = 0; j < 6; ++j) { float d = v[j] - mean; s2 += d * d; }
  #pragma unroll
  for (int off = 32; off > 0; off >>= 1) s2 += __shfl_xor(s2, off);
  float rstd = rsqrtf(s2 * (1.f / E_) + 1e-5f);
  float* ob = oln + (size_t)row * E_;
  #pragma unroll
  for (int j = 0; j < 6; ++j) {
    int e = lane + 64 * j;
    ob[e] = (v[j] - mean) * rstd * lw[e] + lb[e];
  }
}

// ---------------------------------------------------------------------------
// Kernel 7: final GEMM  out[n][j] = sum_e oln[n][e]*fcw[j][e] + fcb[j]
// grid (6, 25) block 256.
// ---------------------------------------------------------------------------
__global__ __launch_bounds__(256) void k_fc(
    const float* __restrict__ oln, const float* __restrict__ fcw,
    const float* __restrict__ fcb, float* __restrict__ out)
{
  const int j0 = blockIdx.x * 64, n0 = blockIdx.y * 64;
  __shared__ float Xs[16][64];   // [e][n]
  __shared__ float Ws[16][64];   // [e][j]
  const int tid = threadIdx.x;
  const int tx = tid & 15, ty = tid >> 4;
  float acc[4][4];
  #pragma unroll
  for (int i = 0; i < 4; ++i)
    #pragma unroll
    for (int j = 0; j < 4; ++j) acc[i][j] = 0.f;

  for (int e0 = 0; e0 < E_; e0 += 16) {
    {
      int nl = tid >> 2, c4 = (tid & 3) * 4;
      int n = n0 + nl;
      float4 v = make_float4(0.f, 0.f, 0.f, 0.f);
      if (n < N_) v = *(const float4*)(oln + (size_t)n * E_ + e0 + c4);
      Xs[c4 + 0][nl] = v.x; Xs[c4 + 1][nl] = v.y;
      Xs[c4 + 2][nl] = v.z; Xs[c4 + 3][nl] = v.w;
      float4 u = *(const float4*)(fcw + (size_t)(j0 + nl) * E_ + e0 + c4);
      Ws[c4 + 0][nl] = u.x; Ws[c4 + 1][nl] = u.y;
      Ws[c4 + 2][nl] = u.z; Ws[c4 + 3][nl] = u.w;
    }
    __syncthreads();
    #pragma unroll
    for (int cc = 0; cc < 16; ++cc) {
      float4 xv = *(const float4*)(&Xs[cc][tx * 4]);
      float4 wv4 = *(const float4*)(&Ws[cc][ty * 4]);
      float xa[4] = {xv.x, xv.y, xv.z, xv.w};
      float wa[4] = {wv4.x, wv4.y, wv4.z, wv4.w};
      #pragma unroll
      for (int i = 0; i < 4; ++i)
        #pragma unroll
        for (int j = 0; j < 4; ++j)
          acc[i][j] += wa[i] * xa[j];
    }
    __syncthreads();
  }
  #pragma unroll
  for (int jj = 0; jj < 4; ++jj) {
    int n = n0 + tx * 4 + jj;
    if (n < N_) {
      int jc = j0 + ty * 4;
      float4 o;
      o.x = acc[0][jj] + fcb[jc + 0];
      o.y = acc[1][jj] + fcb[jc + 1];
      o.z = acc[2][jj] + fcb[jc + 2];
      o.w = acc[3][jj] + fcb[jc + 3];
      *(float4*)(out + (size_t)n * E_ + jc) = o;
    }
  }
}

// ---------------------------------------------------------------------------
extern "C" void kernel_launch(void* const* d_in, const int* in_sizes, int n_in,
                              void* d_out, int out_size, void* d_ws, size_t ws_size,
                              hipStream_t stream)
{
  const float* x   = (const float*)d_in[0];
  const float* wq  = (const float*)d_in[1];
  const float* wk  = (const float*)d_in[2];
  const float* wv  = (const float*)d_in[3];
  const float* qw  = (const float*)d_in[4];
  const float* qb  = (const float*)d_in[5];
  const float* kw  = (const float*)d_in[6];
  const float* kb  = (const float*)d_in[7];
  const float* vw  = (const float*)d_in[8];
  const float* vb  = (const float*)d_in[9];
  const float* ow  = (const float*)d_in[10];
  const float* obp = (const float*)d_in[11];
  const float* fcw = (const float*)d_in[12];
  const float* fcb = (const float*)d_in[13];
  float* out = (float*)d_out;
  float* ws  = (float*)d_ws;

  // ws layout (floats):
  //  slots 0..5: [2p+c] adder partials; after reduce, slot 2p = Y_p,
  //  after lnall, slot 2p+1 = Z_p.  Then obuf, oln, partials, stats.
  float* obuf  = ws + 6 * EN;
  float* oln   = ws + 7 * EN;
  float* part  = ws + 8 * EN;                  // 3*591*2
  float* stats = part + 3 * NBLK_RED * 2;      // 6

  const float scale = (float)pow(2.0 * D_ * (1.0 - 2.0 / M_PI), -0.5);

  k_adder<<<dim3(6, 50, 6), 256, 0, stream>>>(x, wq, wk, wv, ws);
  k_reduceY<<<dim3(NBLK_RED, 3), 256, 0, stream>>>(ws, part);
  k_stats<<<dim3(3), 256, 0, stream>>>(part, stats);
  k_lnall<<<dim3(NBLK_RED, 3), 256, 0, stream>>>(ws, stats, qw, qb, kw, kb, vw, vb);
  const float* zq = ws + 1 * EN;
  const float* zk = ws + 3 * EN;
  const float* zv = ws + 5 * EN;
  k_attn<<<dim3(48, 7), 256, 0, stream>>>(zq, zk, zv, obuf, scale);
  k_lnlast<<<dim3(394), 256, 0, stream>>>(obuf, ow, obp, oln);
  k_fc<<<dim3(6, 25), 256, 0, stream>>>(oln, fcw, fcb, out);
}